// Round 3
// baseline (522.349 us; speedup 1.0000x reference)
//
#include <hip/hip_runtime.h>
#include <hip/hip_bf16.h>

typedef __attribute__((ext_vector_type(8))) short bf16x8;
typedef __attribute__((ext_vector_type(4))) float f32x4;
typedef __attribute__((ext_vector_type(4))) unsigned int u32x4;

#define NC 32
#define HH 512
#define WWD 512
#define HW (HH * WWD)

#define TH 8
#define TW 32
#define HALO_W 34
#define ROWS 10                        // circular row slots
#define NITER 16                       // 16 * 8 = 128 rows per block
#define NPIX (ROWS * HALO_W)           // 340
#define XUNITS (NPIX * 4)              // 1360 16B-units
#define WOFF (XUNITS * 16)             // 21760
#define NU8  (8 * HALO_W * 4)          // 1088 units, steady state
// LDS total: 21760 + 9*4*32*16 = 40192 B -> 4 blocks/CU

__device__ __forceinline__ unsigned short f2bf(float f) {
    unsigned u = __builtin_bit_cast(unsigned, f);
    u += 0x7FFFu + ((u >> 16) & 1u);   // round-to-nearest-even
    return (unsigned short)(u >> 16);
}

// linear, conflict-free: [icg][pixel] 16B units
__device__ __forceinline__ int xbyte(int p, int g) {
    return (g * NPIX + p) * 16;
}

__global__ __launch_bounds__(512, 8)
void conv3x3_mfma(const float* __restrict__ x,
                  const float* __restrict__ wk,
                  float* __restrict__ out) {
    __shared__ __align__(16) char smem[WOFF + 9 * 4 * 32 * 16];  // 40192 B

    const int tid   = threadIdx.x;
    const int lane  = tid & 63;
    const int wv    = tid >> 6;
    const int col16 = lane & 15;
    const int g4    = lane >> 4;

    const int w0    = blockIdx.x * TW;
    const int hbase = blockIdx.y * (TH * NITER);
    const int b     = blockIdx.z;

    const float* xb = x + (size_t)b * NC * HW;
    float* ob = out + (size_t)b * NC * HW;

    float sv[3][8];

    // ---- prologue: load rows hbase-1 .. hbase+8 -> slots 0..9 (slot = (r_rel+1)%10) ----
    #pragma unroll
    for (int k = 0; k < 3; ++k) {
        int u = tid + k * 512;
        if (u < XUNITS) {
            int g  = u / NPIX;
            int p  = u - g * NPIX;
            int hh = p / HALO_W;
            int ww = p - hh * HALO_W;
            int row = hbase + hh - 1;
            int cl  = w0 + ww - 1;
            bool ok = ((unsigned)row < (unsigned)HH) && ((unsigned)cl < (unsigned)WWD);
            const float* src = xb + (g * 8) * HW + row * WWD + cl;
            #pragma unroll
            for (int j = 0; j < 8; ++j) {
                float t = 0.f;
                if (ok) t = src[j * HW];
                sv[k][j] = t;
            }
        }
    }

    // ---- weights -> LDS bf16, [tap][icg][oc] 16B units (slot = oc&7: conflict-free) ----
    {
        unsigned short* wl = (unsigned short*)(smem + WOFF);
        for (int i = tid; i < 9216; i += 512) {
            int oc = i / 288; int rem = i - oc * 288;
            int ic = rem / 9; int tap = rem - ic * 9;
            wl[((tap * 4 + (ic >> 3)) * 32 + oc) * 8 + (ic & 7)] = f2bf(wk[i]);
        }
    }

    // ---- write prologue rows to LDS ----
    #pragma unroll
    for (int k = 0; k < 3; ++k) {
        int u = tid + k * 512;
        if (u < XUNITS) {
            int g = u / NPIX;
            int p = u - g * NPIX;
            unsigned q0 = (unsigned)f2bf(sv[k][0]) | ((unsigned)f2bf(sv[k][1]) << 16);
            unsigned q1 = (unsigned)f2bf(sv[k][2]) | ((unsigned)f2bf(sv[k][3]) << 16);
            unsigned q2 = (unsigned)f2bf(sv[k][4]) | ((unsigned)f2bf(sv[k][5]) << 16);
            unsigned q3 = (unsigned)f2bf(sv[k][6]) | ((unsigned)f2bf(sv[k][7]) << 16);
            u32x4 q = { q0, q1, q2, q3 };
            *(u32x4*)(smem + xbyte(p, g)) = q;
        }
    }

    // ---- prefetch rows for iter 1: rows hbase+9+hh ----
    #pragma unroll
    for (int k = 0; k < 3; ++k) {
        int u = tid + k * 512;
        if (u < NU8) {
            int g  = u / (8 * HALO_W);
            int p  = u - g * (8 * HALO_W);
            int hh = p / HALO_W;
            int ww = p - hh * HALO_W;
            int row = hbase + 9 + hh;
            int cl  = w0 + ww - 1;
            bool ok = ((unsigned)row < (unsigned)HH) && ((unsigned)cl < (unsigned)WWD);
            const float* src = xb + (g * 8) * HW + row * WWD + cl;
            #pragma unroll
            for (int j = 0; j < 8; ++j) {
                float t = 0.f;
                if (ok) t = src[j * HW];
                sv[k][j] = t;
            }
        }
    }

    __syncthreads();   // weights + tile 0 visible

    int srbase = wv;   // slot of first needed row = (8*it + wv) % 10
    int wb = 0;        // write slot base at tail of iter it = (8*(it+1)) % 10

    for (int it = 0; it < NITER; ++it) {
        // ---- compute: wave wv owns output row hbase+8*it+wv, 32 columns ----
        f32x4 acc[2][2];
        {
            f32x4 z = {0.f, 0.f, 0.f, 0.f};
            acc[0][0] = z; acc[0][1] = z; acc[1][0] = z; acc[1][1] = z;
        }

        int rs[3];
        #pragma unroll
        for (int dh = 0; dh < 3; ++dh) {
            int s = srbase + dh; if (s >= ROWS) s -= ROWS;
            rs[dh] = s * HALO_W;
        }

        const char* wls = smem + WOFF;
        #pragma unroll
        for (int dh = 0; dh < 3; ++dh) {
            #pragma unroll
            for (int dw = 0; dw < 3; ++dw) {
                const int tap = dh * 3 + dw;
                bf16x8 b0 = *(const bf16x8*)(wls + ((tap * 4 + g4) * 32 + col16) * 16);
                bf16x8 b1 = *(const bf16x8*)(wls + ((tap * 4 + g4) * 32 + 16 + col16) * 16);
                #pragma unroll
                for (int m = 0; m < 2; ++m) {
                    int p = rs[dh] + m * 16 + col16 + dw;
                    bf16x8 a = *(const bf16x8*)(smem + xbyte(p, g4));
                    acc[m][0] = __builtin_amdgcn_mfma_f32_16x16x32_bf16(a, b0, acc[m][0], 0, 0, 0);
                    acc[m][1] = __builtin_amdgcn_mfma_f32_16x16x32_bf16(a, b1, acc[m][1], 0, 0, 0);
                }
            }
        }

        // ---- store (plain f32x4; L2 merges to full lines) ----
        {
            float* orow = ob + (size_t)(hbase + it * 8 + wv) * WWD + w0;
            #pragma unroll
            for (int m = 0; m < 2; ++m) {
                #pragma unroll
                for (int n = 0; n < 2; ++n) {
                    float* pp = orow + (size_t)(n * 16 + col16) * HW + m * 16 + g4 * 4;
                    *(f32x4*)pp = acc[m][n];
                }
            }
        }

        if (it < NITER - 1) {
            __syncthreads();   // all waves done reading tile `it`

            // ---- write prefetched rows (for iter it+1) into circular slots ----
            #pragma unroll
            for (int k = 0; k < 3; ++k) {
                int u = tid + k * 512;
                if (u < NU8) {
                    int g  = u / (8 * HALO_W);
                    int p  = u - g * (8 * HALO_W);
                    int hh = p / HALO_W;
                    int ww = p - hh * HALO_W;
                    int slot = wb + hh; if (slot >= ROWS) slot -= ROWS;
                    int pp = slot * HALO_W + ww;
                    unsigned q0 = (unsigned)f2bf(sv[k][0]) | ((unsigned)f2bf(sv[k][1]) << 16);
                    unsigned q1 = (unsigned)f2bf(sv[k][2]) | ((unsigned)f2bf(sv[k][3]) << 16);
                    unsigned q2 = (unsigned)f2bf(sv[k][4]) | ((unsigned)f2bf(sv[k][5]) << 16);
                    unsigned q3 = (unsigned)f2bf(sv[k][6]) | ((unsigned)f2bf(sv[k][7]) << 16);
                    u32x4 q = { q0, q1, q2, q3 };
                    *(u32x4*)(smem + xbyte(pp, g)) = q;
                }
            }
            wb += 8; if (wb >= ROWS) wb -= ROWS;

            // ---- prefetch rows for iter it+2 ----
            if (it < NITER - 2) {
                #pragma unroll
                for (int k = 0; k < 3; ++k) {
                    int u = tid + k * 512;
                    if (u < NU8) {
                        int g  = u / (8 * HALO_W);
                        int p  = u - g * (8 * HALO_W);
                        int hh = p / HALO_W;
                        int ww = p - hh * HALO_W;
                        int row = hbase + 8 * it + 17 + hh;
                        int cl  = w0 + ww - 1;
                        bool ok = ((unsigned)row < (unsigned)HH) && ((unsigned)cl < (unsigned)WWD);
                        const float* src = xb + (g * 8) * HW + row * WWD + cl;
                        #pragma unroll
                        for (int j = 0; j < 8; ++j) {
                            float t = 0.f;
                            if (ok) t = src[j * HW];
                            sv[k][j] = t;
                        }
                    }
                }
            }

            __syncthreads();   // tile it+1 ready
        }

        srbase += 8; if (srbase >= ROWS) srbase -= ROWS;
    }
}

extern "C" void kernel_launch(void* const* d_in, const int* in_sizes, int n_in,
                              void* d_out, int out_size, void* d_ws, size_t ws_size,
                              hipStream_t stream) {
    const float* x  = (const float*)d_in[0];
    const float* wk = (const float*)d_in[1];
    float* out = (float*)d_out;
    dim3 grid(WWD / TW, HH / (TH * NITER), 16);  // (16, 4, 16) = 1024 blocks, 4/CU
    conv3x3_mfma<<<grid, 512, 0, stream>>>(x, wk, out);
}

// Round 4
// 284.030 us; speedup vs baseline: 1.8391x; 1.8391x over previous
//
#include <hip/hip_runtime.h>
#include <hip/hip_bf16.h>

typedef __attribute__((ext_vector_type(8))) short bf16x8;
typedef __attribute__((ext_vector_type(4))) float f32x4;
typedef __attribute__((ext_vector_type(4))) unsigned int u32x4;

#define NC 32
#define HH 512
#define WWD 512
#define HW (HH * WWD)

#define TH 8
#define TW 64
#define HALO_W 66
#define ROWS 10                        // circular row slots
#define NITER 16                       // 16 * 8 = 128 rows per block
#define NPIX (ROWS * HALO_W)           // 660
#define XUNITS (NPIX * 4)              // 2640 16B-units (prologue)
#define WOFF (NPIX * 64)               // 42240: weights after x tile
#define NU8  (8 * HALO_W * 4)          // 2112 units, steady state
// LDS total: 42240 + 9*4*32*16 = 60672 B -> 2 blocks/CU (LDS-bound)

__device__ __forceinline__ unsigned short f2bf(float f) {
    unsigned u = __builtin_bit_cast(unsigned, f);
    u += 0x7FFFu + ((u >> 16) & 1u);   // round-to-nearest-even
    return (unsigned short)(u >> 16);
}

// linear, conflict-free: [icg][pixel] 16B units
__device__ __forceinline__ int xbyte(int p, int g) {
    return (g * NPIX + p) * 16;
}

#define SCHED() __builtin_amdgcn_sched_barrier(0)

__global__ __launch_bounds__(512, 4)
void conv3x3_mfma(const float* __restrict__ x,
                  const float* __restrict__ wk,
                  float* __restrict__ out) {
    __shared__ __align__(16) char smem[WOFF + 9 * 4 * 32 * 16];  // 60672 B

    const int tid   = threadIdx.x;
    const int lane  = tid & 63;
    const int wv    = tid >> 6;
    const int col16 = lane & 15;
    const int g4    = lane >> 4;

    const int w0    = blockIdx.x * TW;
    const int hbase = blockIdx.y * (TH * NITER);
    const int b     = blockIdx.z;

    const float* xb = x + (size_t)b * NC * HW;
    float* ob = out + (size_t)b * NC * HW;

    float sv[5][8];   // steady-state staging: ceil(2112/512)=5 units/thread

    // ================= prologue =================
    {
        float svp[6][8];
        // load rows hbase-1 .. hbase+8 -> slots 0..9
        #pragma unroll
        for (int k = 0; k < 6; ++k) {
            int u = tid + k * 512;
            if (u < XUNITS) {
                int g  = u / NPIX;
                int p  = u - g * NPIX;
                int hh = p / HALO_W;
                int ww = p - hh * HALO_W;
                int row = hbase + hh - 1;
                int cl  = w0 + ww - 1;
                bool ok = ((unsigned)row < (unsigned)HH) && ((unsigned)cl < (unsigned)WWD);
                const float* src = xb + (g * 8) * HW + row * WWD + cl;
                #pragma unroll
                for (int j = 0; j < 8; ++j) {
                    float t = 0.f;
                    if (ok) t = src[j * HW];
                    svp[k][j] = t;
                }
            }
        }
        // weights -> LDS bf16, [tap][icg][oc] 16B units
        {
            unsigned short* wl = (unsigned short*)(smem + WOFF);
            for (int i = tid; i < 9216; i += 512) {
                int oc = i / 288; int rem = i - oc * 288;
                int ic = rem / 9; int tap = rem - ic * 9;
                wl[((tap * 4 + (ic >> 3)) * 32 + oc) * 8 + (ic & 7)] = f2bf(wk[i]);
            }
        }
        // write prologue rows to LDS
        #pragma unroll
        for (int k = 0; k < 6; ++k) {
            int u = tid + k * 512;
            if (u < XUNITS) {
                int g = u / NPIX;
                int p = u - g * NPIX;
                unsigned q0 = (unsigned)f2bf(svp[k][0]) | ((unsigned)f2bf(svp[k][1]) << 16);
                unsigned q1 = (unsigned)f2bf(svp[k][2]) | ((unsigned)f2bf(svp[k][3]) << 16);
                unsigned q2 = (unsigned)f2bf(svp[k][4]) | ((unsigned)f2bf(svp[k][5]) << 16);
                unsigned q3 = (unsigned)f2bf(svp[k][6]) | ((unsigned)f2bf(svp[k][7]) << 16);
                u32x4 q = { q0, q1, q2, q3 };
                *(u32x4*)(smem + xbyte(p, g)) = q;
            }
        }
    }
    // issue loads for tile 1 (rows hbase+9..hbase+16)
    #pragma unroll
    for (int k = 0; k < 5; ++k) {
        int u = tid + k * 512;
        if (u < NU8) {
            int g  = u / (8 * HALO_W);
            int p  = u - g * (8 * HALO_W);
            int hh = p / HALO_W;
            int ww = p - hh * HALO_W;
            int row = hbase + 9 + hh;
            int cl  = w0 + ww - 1;
            bool ok = ((unsigned)row < (unsigned)HH) && ((unsigned)cl < (unsigned)WWD);
            const float* src = xb + (g * 8) * HW + row * WWD + cl;
            #pragma unroll
            for (int j = 0; j < 8; ++j) {
                float t = 0.f;
                if (ok) t = src[j * HW];
                sv[k][j] = t;
            }
        }
    }

    __syncthreads();   // prologue only: weights + tile 0 visible (full drain OK here)

    int srbase = wv;   // slot of first needed row = (8*it + wv) % 10
    int wb = 0;        // write slot base at tail of iter it = (8*it) % 10

    for (int it = 0; it < NITER; ++it) {
        // ---- compute(it): wave wv owns output row hbase+8*it+wv, 64 columns ----
        f32x4 acc[4][2];
        #pragma unroll
        for (int m = 0; m < 4; ++m) {
            f32x4 z = {0.f, 0.f, 0.f, 0.f};
            acc[m][0] = z; acc[m][1] = z;
        }

        int rs[3];
        #pragma unroll
        for (int dh = 0; dh < 3; ++dh) {
            int s = srbase + dh; if (s >= ROWS) s -= ROWS;
            rs[dh] = s * HALO_W;
        }

        const char* wls = smem + WOFF;
        #pragma unroll
        for (int dh = 0; dh < 3; ++dh) {
            #pragma unroll
            for (int dw = 0; dw < 3; ++dw) {
                const int tap = dh * 3 + dw;
                bf16x8 b0 = *(const bf16x8*)(wls + ((tap * 4 + g4) * 32 + col16) * 16);
                bf16x8 b1 = *(const bf16x8*)(wls + ((tap * 4 + g4) * 32 + 16 + col16) * 16);
                #pragma unroll
                for (int m = 0; m < 4; ++m) {
                    int p = rs[dh] + m * 16 + col16 + dw;
                    bf16x8 a = *(const bf16x8*)(smem + xbyte(p, g4));
                    acc[m][0] = __builtin_amdgcn_mfma_f32_16x16x32_bf16(a, b0, acc[m][0], 0, 0, 0);
                    acc[m][1] = __builtin_amdgcn_mfma_f32_16x16x32_bf16(a, b1, acc[m][1], 0, 0, 0);
                }
            }
        }

        // ---- store (8 f32x4 vmem instrs — the vmcnt(8) allowance below) ----
        {
            float* orow = ob + (size_t)(hbase + it * 8 + wv) * WWD + w0;
            #pragma unroll
            for (int m = 0; m < 4; ++m) {
                #pragma unroll
                for (int n = 0; n < 2; ++n) {
                    float* pp = orow + (size_t)(n * 16 + col16) * HW + m * 16 + g4 * 4;
                    *(f32x4*)pp = acc[m][n];
                }
            }
        }

        if (it < NITER - 1) {
            // ---- bar A: all waves done reading tile `it`; NO vmem drain ----
            asm volatile("s_waitcnt lgkmcnt(0)" ::: "memory");
            SCHED();
            __builtin_amdgcn_s_barrier();
            SCHED();

            // loads(it+1) retired: in-order vmcnt; the 8 newest = this iter's stores
            asm volatile("s_waitcnt vmcnt(8)" ::: "memory");
            SCHED();

            // ---- write rows for iter it+1 into circular slots ----
            #pragma unroll
            for (int k = 0; k < 5; ++k) {
                int u = tid + k * 512;
                if (u < NU8) {
                    int g  = u / (8 * HALO_W);
                    int p  = u - g * (8 * HALO_W);
                    int hh = p / HALO_W;
                    int ww = p - hh * HALO_W;
                    int slot = wb + hh; if (slot >= ROWS) slot -= ROWS;
                    int pp = slot * HALO_W + ww;
                    unsigned q0 = (unsigned)f2bf(sv[k][0]) | ((unsigned)f2bf(sv[k][1]) << 16);
                    unsigned q1 = (unsigned)f2bf(sv[k][2]) | ((unsigned)f2bf(sv[k][3]) << 16);
                    unsigned q2 = (unsigned)f2bf(sv[k][4]) | ((unsigned)f2bf(sv[k][5]) << 16);
                    unsigned q3 = (unsigned)f2bf(sv[k][6]) | ((unsigned)f2bf(sv[k][7]) << 16);
                    u32x4 q = { q0, q1, q2, q3 };
                    *(u32x4*)(smem + xbyte(pp, g)) = q;
                }
            }
            wb += 8; if (wb >= ROWS) wb -= ROWS;

            // ---- issue loads for iter it+2 (stay in flight across bar B) ----
            if (it < NITER - 2) {
                #pragma unroll
                for (int k = 0; k < 5; ++k) {
                    int u = tid + k * 512;
                    if (u < NU8) {
                        int g  = u / (8 * HALO_W);
                        int p  = u - g * (8 * HALO_W);
                        int hh = p / HALO_W;
                        int ww = p - hh * HALO_W;
                        int row = hbase + 8 * it + 17 + hh;
                        int cl  = w0 + ww - 1;
                        bool ok = ((unsigned)row < (unsigned)HH) && ((unsigned)cl < (unsigned)WWD);
                        const float* src = xb + (g * 8) * HW + row * WWD + cl;
                        #pragma unroll
                        for (int j = 0; j < 8; ++j) {
                            float t = 0.f;
                            if (ok) t = src[j * HW];
                            sv[k][j] = t;
                        }
                    }
                }
            }

            // ---- bar B: tile it+1 LDS-writes visible; loads NOT drained ----
            asm volatile("s_waitcnt lgkmcnt(0)" ::: "memory");
            SCHED();
            __builtin_amdgcn_s_barrier();
            SCHED();
        }

        srbase += 8; if (srbase >= ROWS) srbase -= ROWS;
    }
}

extern "C" void kernel_launch(void* const* d_in, const int* in_sizes, int n_in,
                              void* d_out, int out_size, void* d_ws, size_t ws_size,
                              hipStream_t stream) {
    const float* x  = (const float*)d_in[0];
    const float* wk = (const float*)d_in[1];
    float* out = (float*)d_out;
    dim3 grid(WWD / TW, HH / (TH * NITER), 16);  // (8, 4, 16) = 512 blocks, 2/CU
    conv3x3_mfma<<<grid, 512, 0, stream>>>(x, wk, out);
}